// Round 2
// baseline (568.303 us; speedup 1.0000x reference)
//
#include <hip/hip_runtime.h>
#include <cstdint>
#include <cstddef>

#define D_DIM 20000
#define C4    5000           // D_DIM / 4 float4 chunks per row
#define K_SEL 1000
#define BLK   1024
#define JPT   5              // float4 chunks per thread: BLK*JPT = 5120 >= C4
#define NW    (BLK / 64)     // 16 waves per block
#define CAP   1024           // candidate buffer for exact bracket select

// Bracket for the k=1000 / n=20000 order statistic of N(0,1):
// mean 1.6449, sd 0.01495 -> +/- 8 sigma. Pure performance heuristic:
// rows outside the bracket take the exact bitwise-search fallback below,
// so correctness holds for ANY input.
#define T_LO_F 1.5253f
#define T_HI_F 1.7645f

typedef float vf4 __attribute__((ext_vector_type(4)));   // native vector: OK for nontemporal builtin

// monotonic float -> uint key (larger float => larger key)
__device__ __forceinline__ uint32_t f2k(float f) {
    uint32_t b = __float_as_uint(f);
    return (b & 0x80000000u) ? ~b : (b | 0x80000000u);
}
__device__ __forceinline__ float k2f(uint32_t k) {
    uint32_t b = (k & 0x80000000u) ? (k & 0x7FFFFFFFu) : ~k;
    return __uint_as_float(b);
}

__device__ __forceinline__ uint32_t wave_sum(uint32_t v) {
    #pragma unroll
    for (int d = 32; d >= 1; d >>= 1) v += __shfl_xor(v, d, 64);
    return v;
}

__global__ void __launch_bounds__(BLK, 8)   // 8 waves/EU -> 2 blocks/CU (32 waves), 64-VGPR cap
wta_kernel(const float* __restrict__ in, float* __restrict__ out) {
    const int row  = blockIdx.x;
    const int tid  = threadIdx.x;
    const int lane = tid & 63;
    const int wid  = tid >> 6;

    __shared__ uint32_t cand[CAP];           // 4 KB
    __shared__ uint32_t ccnt;                // candidates collected
    __shared__ uint32_t s_hi;                // count of keys > KHI
    __shared__ uint32_t s_t0;                // fallback reduce slots
    __shared__ uint32_t s_t1;
    __shared__ uint32_t bc[3];               // 0: T, 1: budget, 2: m (count == T)
    __shared__ uint32_t waveTot[NW];

    const float4* in4  = (const float4*)(in  + (size_t)row * D_DIM);
    vf4*          out4 = (vf4*)         (out + (size_t)row * D_DIM);

    if (tid == 0) { ccnt = 0u; s_hi = 0u; }
    __syncthreads();

    const uint32_t KHI = f2k(T_HI_F);
    const uint32_t KLO = f2k(T_LO_F);

    // ---- single pass: load row into registers, count > KHI, collect bracket ----
    uint32_t keys[JPT * 4];
    #pragma unroll
    for (int j = 0; j < JPT; ++j) {
        int c = j * BLK + tid;
        if (c < C4) {
            float4 v = in4[c];
            keys[4*j+0] = f2k(v.x);
            keys[4*j+1] = f2k(v.y);
            keys[4*j+2] = f2k(v.z);
            keys[4*j+3] = f2k(v.w);
        } else {
            keys[4*j+0] = 0u; keys[4*j+1] = 0u;
            keys[4*j+2] = 0u; keys[4*j+3] = 0u;   // key 0 = -NaN, below all real data
        }
    }

    uint32_t cnt_hi = 0;
    #pragma unroll
    for (int e = 0; e < JPT * 4; ++e) {
        uint32_t k = keys[e];
        cnt_hi += (k > KHI) ? 1u : 0u;
        if (k > KLO && k <= KHI) {
            uint32_t idx = atomicAdd(&ccnt, 1u);
            if (idx < CAP) cand[idx] = k;
        }
    }
    uint32_t wsum = wave_sum(cnt_hi);
    if (lane == 0) atomicAdd(&s_hi, wsum);
    __syncthreads();

    const uint32_t hi = s_hi;
    const uint32_t cm = ccnt;

    if (hi < K_SEL && K_SEL <= hi + cm && cm <= CAP) {
        // ---- exact select among the bracket candidates (expected ~490) ----
        const uint32_t kp = K_SEL - hi;      // rank of target within cand
        for (uint32_t idx = (uint32_t)tid; idx < cm; idx += BLK) {
            uint32_t x = cand[idx];
            uint32_t gt = 0, eq = 0;
            for (uint32_t j = 0; j < cm; ++j) {
                uint32_t y = cand[j];          // broadcast read, conflict-free
                gt += (y > x) ? 1u : 0u;
                eq += (y == x) ? 1u : 0u;
            }
            if (gt < kp && kp <= gt + eq) {    // unique value-class wins
                bc[0] = x;                     // T (kth-largest key)
                bc[1] = kp - gt;               // budget among == T
                bc[2] = eq;                    // m
            }
        }
        __syncthreads();
    } else {
        // ---- exact fallback for any input: bitwise threshold search over
        // register-resident keys (32 block reductions). Never taken when the
        // bracket holds; correctness-only path.
        uint32_t prefix = 0;
        for (int b = 31; b >= 0; --b) {
            uint32_t probe = prefix | (1u << b);
            uint32_t c = 0;
            #pragma unroll
            for (int e = 0; e < JPT * 4; ++e) c += (keys[e] >= probe) ? 1u : 0u;
            uint32_t t = wave_sum(c);
            if (tid == 0) s_t0 = 0u;
            __syncthreads();
            if (lane == 0) atomicAdd(&s_t0, t);
            __syncthreads();
            uint32_t total = s_t0;
            __syncthreads();
            if (total >= K_SEL) prefix = probe;
        }
        uint32_t g = 0, q = 0;
        #pragma unroll
        for (int e = 0; e < JPT * 4; ++e) {
            g += (keys[e] >  prefix) ? 1u : 0u;
            q += (keys[e] == prefix) ? 1u : 0u;
        }
        uint32_t tg = wave_sum(g);
        uint32_t tq = wave_sum(q);
        if (tid == 0) { s_t0 = 0u; s_t1 = 0u; }
        __syncthreads();
        if (lane == 0) { atomicAdd(&s_t0, tg); atomicAdd(&s_t1, tq); }
        __syncthreads();
        if (tid == 0) { bc[0] = prefix; bc[1] = K_SEL - s_t0; bc[2] = s_t1; }
        __syncthreads();
    }

    const uint32_t T      = bc[0];             // exact K-th largest key
    const uint32_t budget = bc[1];             // how many keys == T to keep
    const uint32_t m      = bc[2];             // how many keys == T exist

    if (m == budget) {
        // ---- fast path: keep everything >= T (bit-exact pass-through) ----
        #pragma unroll
        for (int j = 0; j < JPT; ++j) {
            int c = j * BLK + tid;
            if (c < C4) {
                uint32_t k0 = keys[4*j+0], k1 = keys[4*j+1];
                uint32_t k2 = keys[4*j+2], k3 = keys[4*j+3];
                vf4 o;
                o.x = (k0 >= T) ? k2f(k0) : 0.0f;
                o.y = (k1 >= T) ? k2f(k1) : 0.0f;
                o.z = (k2 >= T) ? k2f(k2) : 0.0f;
                o.w = (k3 >= T) ? k2f(k3) : 0.0f;
                __builtin_nontemporal_store(o, &out4[c]);
            }
        }
    } else {
        // ---- rare tie path: among keys == T keep only the `budget` smallest
        // global indices (matches jax.lax.top_k stable tie-break). Chunk order
        // == (j, tid) order == increasing column order, so an ordered block
        // scan gives exact ranks.
        uint32_t running = 0;
        #pragma unroll
        for (int j = 0; j < JPT; ++j) {
            int c = j * BLK + tid;
            bool valid = (c < C4);
            uint32_t k0 = keys[4*j+0], k1 = keys[4*j+1];
            uint32_t k2 = keys[4*j+2], k3 = keys[4*j+3];
            uint32_t f0 = (valid && k0 == T) ? 1u : 0u;
            uint32_t f1 = (valid && k1 == T) ? 1u : 0u;
            uint32_t f2 = (valid && k2 == T) ? 1u : 0u;
            uint32_t f3 = (valid && k3 == T) ? 1u : 0u;
            uint32_t cnt = f0 + f1 + f2 + f3;

            uint32_t inc = cnt;
            #pragma unroll
            for (int d = 1; d < 64; d <<= 1) {
                uint32_t v = __shfl_up(inc, d, 64);
                if (lane >= d) inc += v;
            }
            if (lane == 63) waveTot[wid] = inc;
            __syncthreads();
            uint32_t waveBefore = 0, blockTot = 0;
            #pragma unroll
            for (int w = 0; w < NW; ++w) {
                uint32_t t = waveTot[w];
                blockTot += t;
                if (w < wid) waveBefore += t;
            }
            uint32_t base = running + waveBefore + (inc - cnt);
            uint32_t r0 = base;
            uint32_t r1 = base + f0;
            uint32_t r2 = base + f0 + f1;
            uint32_t r3 = base + f0 + f1 + f2;
            if (valid) {
                float4 o;
                o.x = (k0 > T || (f0 && r0 < budget)) ? k2f(k0) : 0.0f;
                o.y = (k1 > T || (f1 && r1 < budget)) ? k2f(k1) : 0.0f;
                o.z = (k2 > T || (f2 && r2 < budget)) ? k2f(k2) : 0.0f;
                o.w = (k3 > T || (f3 && r3 < budget)) ? k2f(k3) : 0.0f;
                ((float4*)out4)[c] = o;
            }
            running += blockTot;
            __syncthreads();                   // waveTot reuse next j
        }
    }
}

extern "C" void kernel_launch(void* const* d_in, const int* in_sizes, int n_in,
                              void* d_out, int out_size, void* d_ws, size_t ws_size,
                              hipStream_t stream) {
    const float* in  = (const float*)d_in[0];
    float*       out = (float*)d_out;
    const int B = in_sizes[0] / D_DIM;         // 4096 rows
    wta_kernel<<<dim3(B), dim3(BLK), 0, stream>>>(in, out);
}